// Round 5
// baseline (242.276 us; speedup 1.0000x reference)
//
#include <hip/hip_runtime.h>

// Problem constants (fixed by the reference setup)
constexpr int N_IN  = 50000;
constexpr int C     = 64;
constexpr int T     = 8;
constexpr int E     = 800000;
constexpr int N_OUT = 50000;
constexpr int F     = 64;

// Binned permutation-build parameters
constexpr int BINSZ     = 2048;                      // positions per bin
constexpr int NBIN      = (E + BINSZ - 1) / BINSZ;   // 391
constexpr int CHUNK     = 4096;                      // edges per buildperm block
constexpr int BP_BLOCKS = (E + CHUNK - 1) / CHUNK;   // 196

// ---------------------------------------------------------------------------
// Workspace layout (bytes); total ~67.5 MB (ws >= 102.4 MB proven earlier)
// ---------------------------------------------------------------------------
constexpr size_t OFF_NFBF = 0;                      // bf16 [N_IN][64]      6.4 MB
constexpr size_t OFF_KT   = 6400000;                // bf16 [64][512]       64 KB
constexpr size_t OFF_CNT  = OFF_KT + 65536;         // int  [N_OUT+1]       (-> start[])
constexpr size_t OFF_BSUM = OFF_CNT + 200064;       // int  [256]
constexpr size_t OFF_BCUR = OFF_BSUM + 1024;        // int  [NBIN] (padded)
constexpr size_t OFF_RANK = OFF_BCUR + 2048;        // int  [E]             3.2 MB
constexpr size_t OFF_BENT = OFF_RANK + 3200000;     // u32  [E]             3.2 MB (append-order entries)
constexpr size_t OFF_BNW  = OFF_BENT + 3200000;     // f32  [E][8]         25.6 MB (append-order weights)
constexpr size_t OFF_ISRT = OFF_BNW + 25600000;     // int  [E]             3.2 MB
constexpr size_t OFF_WSRT = OFF_ISRT + 3200000;     // f32  [E][8]         25.6 MB
static_assert(OFF_BNW % 16 == 0 && OFF_WSRT % 16 == 0, "f32x4 alignment");

typedef __attribute__((ext_vector_type(8))) short short8;
typedef __attribute__((ext_vector_type(4))) float f32x4;

__device__ inline unsigned short f2bf(float x) {  // fp32 -> bf16, RNE
    unsigned int u = __float_as_uint(x);
    unsigned int r = (u + 0x7FFFu + ((u >> 16) & 1u)) >> 16;
    return (unsigned short)r;
}
__device__ inline float bf2f(unsigned short u) {
    return __uint_as_float(((unsigned int)u) << 16);
}

// ---------------------------------------------------------------------------
// Fused prep:
//   [0, 3125)            nf -> bf16
//   [3125, 3157)         K transpose -> K_T
//   [3157, 6282)         hist + rank:  rank[e] = atomicAdd(cnt[o]) (old value)
// (ef_T transpose pass deleted: buildperm now reads ef directly, coalesced.)
// ---------------------------------------------------------------------------
constexpr int NF_BLOCKS   = N_IN * C / 4 / 256;  // 3125 (exact)
constexpr int KT_BLOCKS   = 32;
constexpr int HIST_BLOCKS = E / 256;             // 3125 (exact)

__global__ __launch_bounds__(256) void prep_kernel(const float* __restrict__ nf,
                                                   const float* __restrict__ Kmat,
                                                   const int* __restrict__ idx,
                                                   unsigned short* __restrict__ nf_bf,
                                                   unsigned short* __restrict__ K_T,
                                                   int* __restrict__ cnt,
                                                   int* __restrict__ rank) {
    const int b   = blockIdx.x;
    const int tid = threadIdx.x;

    if (b < NF_BLOCKS) {
        int i = b * 256 + tid;  // float4 units; 800000 exact
        float4 v = ((const float4*)nf)[i];
        unsigned int u0 = (unsigned int)f2bf(v.x) | ((unsigned int)f2bf(v.y) << 16);
        unsigned int u1 = (unsigned int)f2bf(v.z) | ((unsigned int)f2bf(v.w) << 16);
        ((uint2*)nf_bf)[i] = make_uint2(u0, u1);
    } else if (b < NF_BLOCKS + KT_BLOCKS) {
        for (int k = (b - NF_BLOCKS) * 256 + tid; k < T * C * F; k += KT_BLOCKS * 256) {
            int f = k & 63;
            int c = (k >> 6) & 63;
            int t = k >> 12;
            K_T[f * 512 + t * 64 + c] = f2bf(Kmat[k]);
        }
    } else {
        int e = (b - NF_BLOCKS - KT_BLOCKS) * 256 + tid;  // 800000 exact
        int o = idx[2 * e];
        rank[e] = atomicAdd(&cnt[o], 1);  // rank write is coalesced
    }
}

// ---------------------------------------------------------------------------
// Scan pass A: per-256-chunk exclusive scan in place, chunk totals -> bsum
// ---------------------------------------------------------------------------
__global__ __launch_bounds__(256) void scanA_kernel(int* __restrict__ cnt,
                                                    int* __restrict__ bsum) {
    __shared__ int sh[256];
    const int tid = threadIdx.x;
    int g = blockIdx.x * 256 + tid;
    int v = (g < N_OUT) ? cnt[g] : 0;
    sh[tid] = v;
    __syncthreads();
#pragma unroll
    for (int off = 1; off < 256; off <<= 1) {
        int x = 0;
        if (tid >= off) x = sh[tid - off];
        __syncthreads();
        if (tid >= off) sh[tid] += x;
        __syncthreads();
    }
    int incl = sh[tid];
    if (g < N_OUT) cnt[g] = incl - v;
    if (tid == 255) bsum[blockIdx.x] = incl;
}

// ---------------------------------------------------------------------------
// Scan pass BC: each block adds sum(bsum[0..bi)) to its chunk.
// Block 0 also initializes the bin cursors to the fixed bin bases.
// ---------------------------------------------------------------------------
__global__ __launch_bounds__(256) void scanBC_kernel(int* __restrict__ cnt,
                                                     const int* __restrict__ bsum,
                                                     int* __restrict__ bincur) {
    __shared__ int sh[256];
    const int bi  = blockIdx.x;
    const int tid = threadIdx.x;
    sh[tid] = (tid < bi) ? bsum[tid] : 0;  // nchunks(196) < 256
    __syncthreads();
#pragma unroll
    for (int off = 128; off >= 1; off >>= 1) {
        if (tid < off) sh[tid] += sh[tid + off];
        __syncthreads();
    }
    const int offset = sh[0];
    int g = bi * 256 + tid;
    if (g < N_OUT) cnt[g] = cnt[g] + offset;
    if (bi == 0) {
        if (tid == 0) cnt[N_OUT] = E;
        for (int g2 = tid; g2 < NBIN; g2 += 256) bincur[g2] = g2 * BINSZ;
    }
}

// ---------------------------------------------------------------------------
// buildperm: LDS-staged binned append. Entries (4 B: off(11b)<<16 | in(16b),
// valid since N_IN < 2^16) are flat-copied to monotone run addresses as
// before. NEW: the edge's 8 fp32 weights are read COALESCED from ef (edge
// ids are chunk-contiguous) and written register->global directly at the
// edge's append slot. All writes to a run's lines come from THIS block ->
// one XCD's L2 -> lines are assembled/merged before eviction (unlike the
// round-1 cross-block scatter). No random 64B-line traffic anywhere.
// ---------------------------------------------------------------------------
__global__ __launch_bounds__(256) void buildperm_kernel(const int* __restrict__ idx,
                                                        const int* __restrict__ rank,
                                                        const int* __restrict__ start,
                                                        const float* __restrict__ ef,
                                                        int* __restrict__ bincur,
                                                        unsigned* __restrict__ binent,
                                                        float* __restrict__ binw) {
    __shared__ int hist[NBIN];
    __shared__ int lcnt[NBIN];
    __shared__ int gdel[NBIN];
    __shared__ int sc[512];
    __shared__ unsigned stage[CHUNK];
    __shared__ int gpos[CHUNK];

    const int tid = threadIdx.x;
    const int e0  = blockIdx.x * CHUNK;

    for (int b = tid; b < NBIN; b += 256) { hist[b] = 0; lcnt[b] = 0; }
    __syncthreads();

    int pos_r[16], in_r[16];
#pragma unroll
    for (int k = 0; k < 16; ++k) {
        int e = e0 + k * 256 + tid;
        pos_r[k] = -1;
        if (e < E) {
            int2 oi = ((const int2*)idx)[e];   // {out, in}, coalesced 8B
            int p = start[oi.x] + rank[e];     // start[] gather is 200KB, L2-hot
            pos_r[k] = p;
            in_r[k]  = oi.y;
            atomicAdd(&hist[p >> 11], 1);
        }
    }
    __syncthreads();

    // inclusive scan of hist (padded to 512), 256 threads x 2 elements
    sc[tid]       = (tid < NBIN) ? hist[tid] : 0;
    sc[tid + 256] = (tid + 256 < NBIN) ? hist[tid + 256] : 0;
    __syncthreads();
    for (int off = 1; off < 512; off <<= 1) {
        int a0 = sc[tid], a1 = sc[tid + 256];
        int b0 = (tid >= off) ? sc[tid - off] : 0;
        int b1 = (tid + 256 >= off) ? sc[tid + 256 - off] : 0;
        __syncthreads();
        sc[tid] = a0 + b0;
        sc[tid + 256] = a1 + b1;
        __syncthreads();
    }

    // reserve a contiguous global run per non-empty bin (~391 atomics/block)
    for (int b = tid; b < NBIN; b += 256) {
        int c = hist[b];
        if (c > 0) gdel[b] = atomicAdd(&bincur[b], c);
    }
    __syncthreads();

    // place entries grouped-by-bin in LDS; remember each edge's append slot
    int gp_r[16];
#pragma unroll
    for (int k = 0; k < 16; ++k) {
        if (pos_r[k] >= 0) {
            int p  = pos_r[k];
            int b  = p >> 11;
            int lr = atomicAdd(&lcnt[b], 1);
            int lbase = (b == 0) ? 0 : sc[b - 1];
            int li = lbase + lr;
            stage[li] = ((unsigned)(p & (BINSZ - 1)) << 16) | (unsigned)in_r[k];
            int g = gdel[b] + lr;
            gpos[li] = g;
            gp_r[k]  = g;
        }
    }
    __syncthreads();

    // entry flat copy: consecutive i -> monotone global addresses within runs
    const int tot = sc[NBIN - 1];
    for (int i = tid; i < tot; i += 256)
        binent[gpos[i]] = stage[i];

    // weights: coalesced ef reads (e chunk-contiguous per (t,k)), direct
    // 32B writes at the append slot (block-private runs -> L2 line merge)
#pragma unroll
    for (int k = 0; k < 16; ++k) {
        if (pos_r[k] >= 0) {
            int e = e0 + k * 256 + tid;
            float w[8];
#pragma unroll
            for (int t = 0; t < T; ++t) w[t] = ef[(size_t)t * E + e];
            float4* dst = (float4*)(binw + (size_t)gp_r[k] * 8);
            dst[0] = make_float4(w[0], w[1], w[2], w[3]);
            dst[1] = make_float4(w[4], w[5], w[6], w[7]);
        }
    }
}

// ---------------------------------------------------------------------------
// permfix: block = one bin. Reads append-ordered entries + weights fully
// coalesced; writes each to its exact slot inside the bin's block-EXCLUSIVE
// windows (8KB isorted / 64KB wsorted) -> scatter absorbed/merged by L2.
// ---------------------------------------------------------------------------
__global__ __launch_bounds__(256) void permfix_kernel(const unsigned* __restrict__ binent,
                                                      const float* __restrict__ binw,
                                                      int* __restrict__ isorted,
                                                      float* __restrict__ wsorted) {
    const int base = blockIdx.x * BINSZ;
    const int n = min(BINSZ, E - base);
    for (int i = threadIdx.x; i < n; i += 256) {
        unsigned u = binent[base + i];
        int off = (int)(u >> 16);
        int in  = (int)(u & 0xFFFFu);
        const float4* src = (const float4*)(binw + (size_t)(base + i) * 8);
        float4 w0 = src[0];
        float4 w1 = src[1];
        isorted[base + off] = in;
        float4* dst = (float4*)(wsorted + (size_t)(base + off) * 8);
        dst[0] = w0;
        dst[1] = w1;
    }
}

// ---------------------------------------------------------------------------
// Aggregate (round-2 proven form, 54us): block = 4 waves = 16 output nodes.
//  Phase 1 (per wave, 4 nodes, lane=c):
//    preload 64 isorted entries coalesced, readlane-broadcast; 4-edge unroll
//    -> 4 independent 128 B nf gathers in flight; weights via uniform
//    SEQUENTIAL scalar loads from wsorted (prefetch-friendly s_load stream,
//    not the round-3/4 random ef_T gather).
//  Phase 2 (per wave, one 16-col f-tile):
//    out_tile(16x64) = A(16x512) @ K_T^T via 16 chained mfma_f32_16x16x32_bf16
// ---------------------------------------------------------------------------
__global__ __launch_bounds__(256) void aggregate_kernel(const unsigned short* __restrict__ nf_bf,
                                                        const unsigned short* __restrict__ K_T,
                                                        const int* __restrict__ start,
                                                        const int* __restrict__ isorted,
                                                        const float* __restrict__ wsorted,
                                                        const float* __restrict__ bias,
                                                        float* __restrict__ out) {
    __shared__ unsigned short A_lds[16][520];  // +8 pad

    const int wave = threadIdx.x >> 6;
    const int lane = threadIdx.x & 63;
    const int node_base = blockIdx.x * 16;  // 50000 = 3125*16 exact

    // ---- Phase 1: segment aggregation ----
    for (int q = 0; q < 4; ++q) {
        const int m = wave * 4 + q;
        const int o = node_base + m;
        const int s0 = __builtin_amdgcn_readfirstlane(start[o]);
        const int s1 = __builtin_amdgcn_readfirstlane(start[o + 1]);

        float acc[8] = {0.f, 0.f, 0.f, 0.f, 0.f, 0.f, 0.f, 0.f};

        for (int base = s0; base < s1; base += 64) {
            const int cnt = min(64, s1 - base);
            // coalesced preload of this chunk's input-node ids
            int iv = (base + lane < s1) ? isorted[base + lane] : 0;

            int j = 0;
            for (; j + 4 <= cnt; j += 4) {
                const int i0 = __builtin_amdgcn_readlane(iv, j + 0);
                const int i1 = __builtin_amdgcn_readlane(iv, j + 1);
                const int i2 = __builtin_amdgcn_readlane(iv, j + 2);
                const int i3 = __builtin_amdgcn_readlane(iv, j + 3);
                // 4 independent 128 B gathers in flight
                float x0 = bf2f(nf_bf[(size_t)i0 * 64 + lane]);
                float x1 = bf2f(nf_bf[(size_t)i1 * 64 + lane]);
                float x2 = bf2f(nf_bf[(size_t)i2 * 64 + lane]);
                float x3 = bf2f(nf_bf[(size_t)i3 * 64 + lane]);
                // uniform sequential weight loads (scalar path)
                const float* wp = wsorted +
                    (size_t)__builtin_amdgcn_readfirstlane(base + j) * 8;
#pragma unroll
                for (int t = 0; t < T; ++t) {
                    acc[t] += wp[t] * x0;
                    acc[t] += wp[8 + t] * x1;
                    acc[t] += wp[16 + t] * x2;
                    acc[t] += wp[24 + t] * x3;
                }
            }
            for (; j < cnt; ++j) {
                const int i0 = __builtin_amdgcn_readlane(iv, j);
                float x0 = bf2f(nf_bf[(size_t)i0 * 64 + lane]);
                const float* wp = wsorted +
                    (size_t)__builtin_amdgcn_readfirstlane(base + j) * 8;
#pragma unroll
                for (int t = 0; t < T; ++t) acc[t] += wp[t] * x0;
            }
        }

#pragma unroll
        for (int t = 0; t < T; ++t) A_lds[m][t * 64 + lane] = f2bf(acc[t]);
    }
    __syncthreads();

    // ---- Phase 2: MFMA epilogue; wave handles f-tile [wave*16, wave*16+16) ----
    const int mrow = lane & 15;
    const int kb   = lane >> 4;
    const int fcol = wave * 16 + mrow;

    f32x4 acc4 = {0.f, 0.f, 0.f, 0.f};
#pragma unroll
    for (int s = 0; s < 16; ++s) {
        const int k0 = s * 32 + kb * 8;
        short8 a = *(const short8*)&A_lds[mrow][k0];
        short8 b = *(const short8*)(K_T + (size_t)fcol * 512 + k0);
        acc4 = __builtin_amdgcn_mfma_f32_16x16x32_bf16(a, b, acc4, 0, 0, 0);
    }

    const float bv = bias[fcol];
#pragma unroll
    for (int r = 0; r < 4; ++r) {
        const int m = kb * 4 + r;
        out[(size_t)(node_base + m) * F + fcol] = acc4[r] + bv;
    }
}

// ---------------------------------------------------------------------------
extern "C" void kernel_launch(void* const* d_in, const int* in_sizes, int n_in,
                              void* d_out, int out_size, void* d_ws, size_t ws_size,
                              hipStream_t stream) {
    const float* nf   = (const float*)d_in[0];  // (N_IN, C)
    const float* ef   = (const float*)d_in[1];  // (T, E)
    const int*   idx  = (const int*)d_in[2];    // (E, 2) int32 on device
    const float* Kmat = (const float*)d_in[3];  // (T, C, F)
    const float* bias = (const float*)d_in[4];  // (F,)
    float*       out  = (float*)d_out;          // (N_OUT, F)

    char* ws = (char*)d_ws;
    unsigned short* nf_bf   = (unsigned short*)(ws + OFF_NFBF);
    unsigned short* K_T     = (unsigned short*)(ws + OFF_KT);
    int*            cnt     = (int*)(ws + OFF_CNT);   // becomes start[]
    int*            bsum    = (int*)(ws + OFF_BSUM);
    int*            bincur  = (int*)(ws + OFF_BCUR);
    int*            rank    = (int*)(ws + OFF_RANK);
    unsigned*       binent  = (unsigned*)(ws + OFF_BENT);
    float*          binw    = (float*)(ws + OFF_BNW);
    int*            isorted = (int*)(ws + OFF_ISRT);
    float*          wsorted = (float*)(ws + OFF_WSRT);

    const int nchunks = (N_OUT + 255) / 256;  // 196

    hipMemsetAsync(cnt, 0, (N_OUT + 1) * sizeof(int), stream);
    prep_kernel<<<NF_BLOCKS + KT_BLOCKS + HIST_BLOCKS, 256, 0, stream>>>(
        nf, Kmat, idx, nf_bf, K_T, cnt, rank);
    scanA_kernel<<<nchunks, 256, 0, stream>>>(cnt, bsum);
    scanBC_kernel<<<nchunks, 256, 0, stream>>>(cnt, bsum, bincur);
    buildperm_kernel<<<BP_BLOCKS, 256, 0, stream>>>(idx, rank, cnt, ef, bincur,
                                                    binent, binw);
    permfix_kernel<<<NBIN, 256, 0, stream>>>(binent, binw, isorted, wsorted);
    aggregate_kernel<<<N_OUT / 16, 256, 0, stream>>>(
        nf_bf, K_T, cnt, isorted, wsorted, bias, out);
}

// Round 6
// 182.729 us; speedup vs baseline: 1.3259x; 1.3259x over previous
//
#include <hip/hip_runtime.h>

// Problem constants (fixed by the reference setup)
constexpr int N_IN  = 50000;
constexpr int C     = 64;
constexpr int T     = 8;
constexpr int E     = 800000;
constexpr int N_OUT = 50000;
constexpr int F     = 64;

// Two-level counting-sort parameters
constexpr int CHUNK   = 4096;                        // edges per chunk
constexpr int NCHUNK  = (E + CHUNK - 1) / CHUNK;     // 196
constexpr int NBIN_S  = (N_OUT + 255) / 256;         // 196 bins of 256 nodes
constexpr int LEN_CNT = NBIN_S * NCHUNK;             // 38416 counts entries
constexpr int SCA     = (LEN_CNT + 255) / 256;       // 151 scan chunks

// ---------------------------------------------------------------------------
// Workspace layout (bytes); total ~45.2 MB
// ---------------------------------------------------------------------------
constexpr size_t OFF_NFBF  = 0;                      // bf16 [N_IN][64]     6.4 MB
constexpr size_t OFF_KT    = 6400000;                // bf16 [64][512]      64 KB
constexpr size_t OFF_CNT   = OFF_KT + 65536;         // int [LEN_CNT] counts->offs
constexpr size_t OFF_BSUM  = OFF_CNT + 153664;       // int [SCA]
constexpr size_t OFF_START = OFF_BSUM + 1024;        // int [N_OUT+1]
constexpr size_t OFF_EFT   = OFF_START + 200064;     // f32 [E][8]         25.6 MB
constexpr size_t OFF_ENT   = OFF_EFT + 25600000;     // uint2 [E]           6.4 MB
constexpr size_t OFF_ISRT  = OFF_ENT + 6400000;      // int [E]             3.2 MB
constexpr size_t OFF_EPRM  = OFF_ISRT + 3200000;     // int [E]             3.2 MB
static_assert(OFF_EFT % 16 == 0 && OFF_ENT % 8 == 0, "alignment");

typedef __attribute__((ext_vector_type(8))) short short8;
typedef __attribute__((ext_vector_type(4))) float f32x4;

__device__ inline unsigned short f2bf(float x) {  // fp32 -> bf16, RNE
    unsigned int u = __float_as_uint(x);
    unsigned int r = (u + 0x7FFFu + ((u >> 16) & 1u)) >> 16;
    return (unsigned short)r;
}
__device__ inline float bf2f(unsigned short u) {
    return __uint_as_float(((unsigned int)u) << 16);
}

// ---------------------------------------------------------------------------
// Fused prep:
//   [0, 3125)            nf -> bf16
//   [3125, 3157)         K transpose -> K_T
//   [3157, 6282)         ef transpose -> ef_T[e][8]  (coalesced both sides)
//   [6282, 6478)         per-chunk LDS bin-histogram -> counts[bin][chunk]
// NO global atomics anywhere (round-5's prep spent ~50us on 800K atomicAdds
// at ~15G atomics/s; LDS histograms + a 38K scan replace them).
// ---------------------------------------------------------------------------
constexpr int NF_BLOCKS = N_IN * C / 4 / 256;  // 3125 (exact)
constexpr int KT_BLOCKS = 32;
constexpr int ET_BLOCKS = E / 256;             // 3125 (exact)
constexpr int BH_BLOCKS = NCHUNK;              // 196

__global__ __launch_bounds__(256) void prep_kernel(const float* __restrict__ nf,
                                                   const float* __restrict__ Kmat,
                                                   const float* __restrict__ ef,
                                                   const int* __restrict__ idx,
                                                   unsigned short* __restrict__ nf_bf,
                                                   unsigned short* __restrict__ K_T,
                                                   float* __restrict__ ef_T,
                                                   int* __restrict__ counts) {
    __shared__ int hist[NBIN_S];
    const int b   = blockIdx.x;
    const int tid = threadIdx.x;

    if (b < NF_BLOCKS) {
        int i = b * 256 + tid;  // float4 units; 800000 exact
        float4 v = ((const float4*)nf)[i];
        unsigned int u0 = (unsigned int)f2bf(v.x) | ((unsigned int)f2bf(v.y) << 16);
        unsigned int u1 = (unsigned int)f2bf(v.z) | ((unsigned int)f2bf(v.w) << 16);
        ((uint2*)nf_bf)[i] = make_uint2(u0, u1);
    } else if (b < NF_BLOCKS + KT_BLOCKS) {
        for (int k = (b - NF_BLOCKS) * 256 + tid; k < T * C * F; k += KT_BLOCKS * 256) {
            int f = k & 63;
            int c = (k >> 6) & 63;
            int t = k >> 12;
            K_T[f * 512 + t * 64 + c] = f2bf(Kmat[k]);
        }
    } else if (b < NF_BLOCKS + KT_BLOCKS + ET_BLOCKS) {
        int e = (b - NF_BLOCKS - KT_BLOCKS) * 256 + tid;  // 800000 exact
        float w[8];
#pragma unroll
        for (int t = 0; t < T; ++t) w[t] = ef[(size_t)t * E + e];  // coalesced per t
        float4* dst = (float4*)(ef_T + (size_t)e * 8);
        dst[0] = make_float4(w[0], w[1], w[2], w[3]);
        dst[1] = make_float4(w[4], w[5], w[6], w[7]);
    } else {
        const int c = b - NF_BLOCKS - KT_BLOCKS - ET_BLOCKS;  // chunk id
        for (int i = tid; i < NBIN_S; i += 256) hist[i] = 0;
        __syncthreads();
        const int e0 = c * CHUNK;
        const int n  = min(CHUNK, E - e0);
        for (int i = tid; i < n; i += 256) {
            int o = ((const int2*)idx)[e0 + i].x;
            atomicAdd(&hist[o >> 8], 1);  // LDS atomic, ~2.6-way avg conflict
        }
        __syncthreads();
        for (int i = tid; i < NBIN_S; i += 256)
            counts[i * NCHUNK + c] = hist[i];  // bin-major for the scan
    }
}

// ---------------------------------------------------------------------------
// Scan pass A over counts[LEN_CNT]: per-256-chunk exclusive scan in place.
// ---------------------------------------------------------------------------
__global__ __launch_bounds__(256) void scanA_kernel(int* __restrict__ a,
                                                    int* __restrict__ bsum) {
    __shared__ int sh[256];
    const int tid = threadIdx.x;
    int g = blockIdx.x * 256 + tid;
    int v = (g < LEN_CNT) ? a[g] : 0;
    sh[tid] = v;
    __syncthreads();
#pragma unroll
    for (int off = 1; off < 256; off <<= 1) {
        int x = 0;
        if (tid >= off) x = sh[tid - off];
        __syncthreads();
        if (tid >= off) sh[tid] += x;
        __syncthreads();
    }
    int incl = sh[tid];
    if (g < LEN_CNT) a[g] = incl - v;
    if (tid == 255) bsum[blockIdx.x] = incl;
}

// ---------------------------------------------------------------------------
// Scan pass BC: each block adds sum(bsum[0..bi)).  SCA(151) < 256.
// ---------------------------------------------------------------------------
__global__ __launch_bounds__(256) void scanBC_kernel(int* __restrict__ a,
                                                     const int* __restrict__ bsum) {
    __shared__ int sh[256];
    const int bi  = blockIdx.x;
    const int tid = threadIdx.x;
    sh[tid] = (tid < bi) ? bsum[tid] : 0;
    __syncthreads();
#pragma unroll
    for (int off = 128; off >= 1; off >>= 1) {
        if (tid < off) sh[tid] += sh[tid + off];
        __syncthreads();
    }
    const int offset = sh[0];
    int g = bi * 256 + tid;
    if (g < LEN_CNT) a[g] += offset;
}

// ---------------------------------------------------------------------------
// binscatter: chunk c places its edges into per-(bin,chunk) runs.
// Run length avg 21 edges (168 B) and each run is written by exactly ONE
// block -> lines assembled in that block's L2 before one eviction.
// Entry: {x: loc(8b)<<20 | e(20b), y: in_node}.
// ---------------------------------------------------------------------------
__global__ __launch_bounds__(512) void binscatter_kernel(const int* __restrict__ idx,
                                                         const int* __restrict__ offs,
                                                         uint2* __restrict__ ent) {
    __shared__ int cur[NBIN_S];
    const int tid = threadIdx.x;
    const int c   = blockIdx.x;
    for (int i = tid; i < NBIN_S; i += 512) cur[i] = offs[i * NCHUNK + c];
    __syncthreads();
    const int e0 = c * CHUNK;
    const int n  = min(CHUNK, E - e0);
    for (int i = tid; i < n; i += 512) {
        int2 oi = ((const int2*)idx)[e0 + i];  // {out, in}, coalesced 8B
        int bin = oi.x >> 8;
        int loc = oi.x & 255;
        int pos = atomicAdd(&cur[bin], 1);
        ent[pos] = make_uint2(((unsigned)loc << 20) | (unsigned)(e0 + i),
                              (unsigned)oi.y);
    }
}

// ---------------------------------------------------------------------------
// permfix: block = one bin (256 nodes, window avg ~4082 edges). Two passes
// over the block-EXCLUSIVE window: (1) LDS 256-hist + scan -> node starts
// (writes global start[] as a by-product); (2) scatter entries to exact
// node-sorted slots. All scattered writes confined to the ~16-33KB window
// -> absorbed/merged by this block's L2.
// ---------------------------------------------------------------------------
__global__ __launch_bounds__(512) void permfix_kernel(const int* __restrict__ offs,
                                                      const uint2* __restrict__ ent,
                                                      int* __restrict__ start_g,
                                                      int* __restrict__ isorted,
                                                      int* __restrict__ eperm) {
    __shared__ int hist[256];
    __shared__ int sc[256];
    __shared__ int cur[256];
    const int tid = threadIdx.x;
    const int b   = blockIdx.x;
    const int W0  = offs[b * NCHUNK];
    const int W1  = (b + 1 < NBIN_S) ? offs[(b + 1) * NCHUNK] : E;

    if (tid < 256) hist[tid] = 0;
    __syncthreads();
    for (int i = W0 + tid; i < W1; i += 512)
        atomicAdd(&hist[ent[i].x >> 20], 1);
    __syncthreads();

    // inclusive scan of hist[256] on threads 0-255 (512-thread-safe barriers)
    if (tid < 256) sc[tid] = hist[tid];
    __syncthreads();
    for (int off = 1; off < 256; off <<= 1) {
        int x = 0;
        if (tid < 256 && tid >= off) x = sc[tid - off];
        __syncthreads();
        if (tid < 256 && tid >= off) sc[tid] += x;
        __syncthreads();
    }
    if (tid < 256) {
        int s = W0 + sc[tid] - hist[tid];  // exclusive
        int g = b * 256 + tid;
        if (g < N_OUT) start_g[g] = s;
        cur[tid] = s;
    }
    if (b == NBIN_S - 1 && tid == 0) start_g[N_OUT] = E;
    __syncthreads();

    for (int i = W0 + tid; i < W1; i += 512) {
        uint2 u = ent[i];
        int loc = (int)(u.x >> 20);
        int e   = (int)(u.x & 0xFFFFFu);
        int pos = atomicAdd(&cur[loc], 1);
        isorted[pos] = (int)u.y;
        eperm[pos]   = e;
    }
}

// ---------------------------------------------------------------------------
// Aggregate (round-3 proven form, 62.6us): block = 4 waves = 16 output nodes.
//  Phase 1 (per wave, 4 nodes, lane=c):
//    preload 64 isorted + eperm entries coalesced, readlane-broadcast;
//    4-edge unroll -> 4 independent 128 B nf gathers in flight; weights via
//    wave-uniform scalar loads from ef_T[e*8].
//  Phase 2 (per wave, one 16-col f-tile):
//    out_tile(16x64) = A(16x512) @ K_T^T via 16 chained mfma_f32_16x16x32_bf16
// ---------------------------------------------------------------------------
__global__ __launch_bounds__(256) void aggregate_kernel(const unsigned short* __restrict__ nf_bf,
                                                        const unsigned short* __restrict__ K_T,
                                                        const int* __restrict__ start,
                                                        const int* __restrict__ isorted,
                                                        const int* __restrict__ eperm,
                                                        const float* __restrict__ ef_T,
                                                        const float* __restrict__ bias,
                                                        float* __restrict__ out) {
    __shared__ unsigned short A_lds[16][520];  // +8 pad

    const int wave = threadIdx.x >> 6;
    const int lane = threadIdx.x & 63;
    const int node_base = blockIdx.x * 16;  // 50000 = 3125*16 exact

    // ---- Phase 1: segment aggregation ----
    for (int q = 0; q < 4; ++q) {
        const int m = wave * 4 + q;
        const int o = node_base + m;
        const int s0 = __builtin_amdgcn_readfirstlane(start[o]);
        const int s1 = __builtin_amdgcn_readfirstlane(start[o + 1]);

        float acc[8] = {0.f, 0.f, 0.f, 0.f, 0.f, 0.f, 0.f, 0.f};

        for (int base = s0; base < s1; base += 64) {
            const int cnt = min(64, s1 - base);
            // coalesced preload of this chunk's input-node ids and edge ids
            int iv = (base + lane < s1) ? isorted[base + lane] : 0;
            int ev = (base + lane < s1) ? eperm[base + lane] : 0;

            int j = 0;
            for (; j + 4 <= cnt; j += 4) {
                const int i0 = __builtin_amdgcn_readlane(iv, j + 0);
                const int i1 = __builtin_amdgcn_readlane(iv, j + 1);
                const int i2 = __builtin_amdgcn_readlane(iv, j + 2);
                const int i3 = __builtin_amdgcn_readlane(iv, j + 3);
                // 4 independent 128 B gathers in flight
                float x0 = bf2f(nf_bf[(size_t)i0 * 64 + lane]);
                float x1 = bf2f(nf_bf[(size_t)i1 * 64 + lane]);
                float x2 = bf2f(nf_bf[(size_t)i2 * 64 + lane]);
                float x3 = bf2f(nf_bf[(size_t)i3 * 64 + lane]);
                // wave-uniform scalar weight loads
                const float* w0 = ef_T + (size_t)__builtin_amdgcn_readlane(ev, j + 0) * 8;
                const float* w1 = ef_T + (size_t)__builtin_amdgcn_readlane(ev, j + 1) * 8;
                const float* w2 = ef_T + (size_t)__builtin_amdgcn_readlane(ev, j + 2) * 8;
                const float* w3 = ef_T + (size_t)__builtin_amdgcn_readlane(ev, j + 3) * 8;
#pragma unroll
                for (int t = 0; t < T; ++t) {
                    acc[t] += w0[t] * x0;
                    acc[t] += w1[t] * x1;
                    acc[t] += w2[t] * x2;
                    acc[t] += w3[t] * x3;
                }
            }
            for (; j < cnt; ++j) {
                const int i0 = __builtin_amdgcn_readlane(iv, j);
                float x0 = bf2f(nf_bf[(size_t)i0 * 64 + lane]);
                const float* w0 = ef_T + (size_t)__builtin_amdgcn_readlane(ev, j) * 8;
#pragma unroll
                for (int t = 0; t < T; ++t) acc[t] += w0[t] * x0;
            }
        }

#pragma unroll
        for (int t = 0; t < T; ++t) A_lds[m][t * 64 + lane] = f2bf(acc[t]);
    }
    __syncthreads();

    // ---- Phase 2: MFMA epilogue; wave handles f-tile [wave*16, wave*16+16) ----
    const int mrow = lane & 15;
    const int kb   = lane >> 4;
    const int fcol = wave * 16 + mrow;

    f32x4 acc4 = {0.f, 0.f, 0.f, 0.f};
#pragma unroll
    for (int s = 0; s < 16; ++s) {
        const int k0 = s * 32 + kb * 8;
        short8 a = *(const short8*)&A_lds[mrow][k0];
        short8 b = *(const short8*)(K_T + (size_t)fcol * 512 + k0);
        acc4 = __builtin_amdgcn_mfma_f32_16x16x32_bf16(a, b, acc4, 0, 0, 0);
    }

    const float bv = bias[fcol];
#pragma unroll
    for (int r = 0; r < 4; ++r) {
        const int m = kb * 4 + r;
        out[(size_t)(node_base + m) * F + fcol] = acc4[r] + bv;
    }
}

// ---------------------------------------------------------------------------
extern "C" void kernel_launch(void* const* d_in, const int* in_sizes, int n_in,
                              void* d_out, int out_size, void* d_ws, size_t ws_size,
                              hipStream_t stream) {
    const float* nf   = (const float*)d_in[0];  // (N_IN, C)
    const float* ef   = (const float*)d_in[1];  // (T, E)
    const int*   idx  = (const int*)d_in[2];    // (E, 2) int32 on device
    const float* Kmat = (const float*)d_in[3];  // (T, C, F)
    const float* bias = (const float*)d_in[4];  // (F,)
    float*       out  = (float*)d_out;          // (N_OUT, F)

    char* ws = (char*)d_ws;
    unsigned short* nf_bf   = (unsigned short*)(ws + OFF_NFBF);
    unsigned short* K_T     = (unsigned short*)(ws + OFF_KT);
    int*            counts  = (int*)(ws + OFF_CNT);    // becomes offs[]
    int*            bsum    = (int*)(ws + OFF_BSUM);
    int*            start   = (int*)(ws + OFF_START);
    float*          ef_T    = (float*)(ws + OFF_EFT);
    uint2*          ent     = (uint2*)(ws + OFF_ENT);
    int*            isorted = (int*)(ws + OFF_ISRT);
    int*            eperm   = (int*)(ws + OFF_EPRM);

    // no memset needed: counts/start/ent are fully written by the pipeline
    prep_kernel<<<NF_BLOCKS + KT_BLOCKS + ET_BLOCKS + BH_BLOCKS, 256, 0, stream>>>(
        nf, Kmat, ef, idx, nf_bf, K_T, ef_T, counts);
    scanA_kernel<<<SCA, 256, 0, stream>>>(counts, bsum);
    scanBC_kernel<<<SCA, 256, 0, stream>>>(counts, bsum);
    binscatter_kernel<<<NCHUNK, 512, 0, stream>>>(idx, counts, ent);
    permfix_kernel<<<NBIN_S, 512, 0, stream>>>(counts, ent, start, isorted, eperm);
    aggregate_kernel<<<N_OUT / 16, 256, 0, stream>>>(
        nf_bf, K_T, start, isorted, eperm, ef_T, bias, out);
}

// Round 7
// 181.739 us; speedup vs baseline: 1.3331x; 1.0055x over previous
//
#include <hip/hip_runtime.h>

// Problem constants (fixed by the reference setup)
constexpr int N_IN  = 50000;
constexpr int C     = 64;
constexpr int T     = 8;
constexpr int E     = 800000;
constexpr int N_OUT = 50000;
constexpr int F     = 64;

// Two-level counting-sort parameters
constexpr int CHUNK   = 4096;                        // edges per chunk
constexpr int NCHUNK  = (E + CHUNK - 1) / CHUNK;     // 196
constexpr int NBIN_S  = (N_OUT + 255) / 256;         // 196 bins of 256 nodes
constexpr int LEN_CNT = NBIN_S * NCHUNK;             // 38416 counts entries
constexpr int SCA     = (LEN_CNT + 255) / 256;       // 151 scan chunks

// ---------------------------------------------------------------------------
// Workspace layout (bytes); total ~32.4 MB
// ---------------------------------------------------------------------------
constexpr size_t OFF_NFBF  = 0;                      // bf16 [N_IN][64]     6.4 MB
constexpr size_t OFF_KT    = 6400000;                // bf16 [64][512]      64 KB
constexpr size_t OFF_CNT   = OFF_KT + 65536;         // int [LEN_CNT] counts->offs
constexpr size_t OFF_BSUM  = OFF_CNT + 153664;       // int [SCA]
constexpr size_t OFF_START = OFF_BSUM + 1024;        // int [N_OUT+1]
constexpr size_t OFF_EFH   = OFF_START + 200064;     // f16 [E][8]         12.8 MB
constexpr size_t OFF_ENT   = OFF_EFH + 12800000;     // uint2 [E]           6.4 MB
constexpr size_t OFF_ENT2  = OFF_ENT + 6400000;      // uint2 [E] {in,e}    6.4 MB
static_assert(OFF_EFH % 16 == 0 && OFF_ENT % 16 == 0 && OFF_ENT2 % 16 == 0,
              "alignment");

typedef __attribute__((ext_vector_type(8))) short short8;
typedef __attribute__((ext_vector_type(4))) float f32x4;
typedef __attribute__((ext_vector_type(8))) _Float16 f16x8;

__device__ inline unsigned short f2bf(float x) {  // fp32 -> bf16, RNE
    unsigned int u = __float_as_uint(x);
    unsigned int r = (u + 0x7FFFu + ((u >> 16) & 1u)) >> 16;
    return (unsigned short)r;
}
__device__ inline float bf2f(unsigned short u) {
    return __uint_as_float(((unsigned int)u) << 16);
}

// ---------------------------------------------------------------------------
// Fused prep:
//   [0, 3125)            nf -> bf16
//   [3125, 3157)         K transpose -> K_T
//   [3157, 6282)         ef transpose+convert -> efh[e][8] fp16 (coalesced)
//   [6282, 6478)         per-chunk LDS bin-histogram -> counts[bin][chunk]
// No global atomics anywhere.
// ---------------------------------------------------------------------------
constexpr int NF_BLOCKS = N_IN * C / 4 / 256;  // 3125 (exact)
constexpr int KT_BLOCKS = 32;
constexpr int ET_BLOCKS = E / 256;             // 3125 (exact)
constexpr int BH_BLOCKS = NCHUNK;              // 196

__global__ __launch_bounds__(256) void prep_kernel(const float* __restrict__ nf,
                                                   const float* __restrict__ Kmat,
                                                   const float* __restrict__ ef,
                                                   const int* __restrict__ idx,
                                                   unsigned short* __restrict__ nf_bf,
                                                   unsigned short* __restrict__ K_T,
                                                   _Float16* __restrict__ efh,
                                                   int* __restrict__ counts) {
    __shared__ int hist[NBIN_S];
    const int b   = blockIdx.x;
    const int tid = threadIdx.x;

    if (b < NF_BLOCKS) {
        int i = b * 256 + tid;  // float4 units; 800000 exact
        float4 v = ((const float4*)nf)[i];
        unsigned int u0 = (unsigned int)f2bf(v.x) | ((unsigned int)f2bf(v.y) << 16);
        unsigned int u1 = (unsigned int)f2bf(v.z) | ((unsigned int)f2bf(v.w) << 16);
        ((uint2*)nf_bf)[i] = make_uint2(u0, u1);
    } else if (b < NF_BLOCKS + KT_BLOCKS) {
        for (int k = (b - NF_BLOCKS) * 256 + tid; k < T * C * F; k += KT_BLOCKS * 256) {
            int f = k & 63;
            int c = (k >> 6) & 63;
            int t = k >> 12;
            K_T[f * 512 + t * 64 + c] = f2bf(Kmat[k]);
        }
    } else if (b < NF_BLOCKS + KT_BLOCKS + ET_BLOCKS) {
        int e = (b - NF_BLOCKS - KT_BLOCKS) * 256 + tid;  // 800000 exact
        f16x8 h;
#pragma unroll
        for (int t = 0; t < T; ++t)
            h[t] = (_Float16)ef[(size_t)t * E + e];  // coalesced per t; RNE cvt
        *(f16x8*)(efh + (size_t)e * 8) = h;          // 16B coalesced store
    } else {
        const int c = b - NF_BLOCKS - KT_BLOCKS - ET_BLOCKS;  // chunk id
        for (int i = tid; i < NBIN_S; i += 256) hist[i] = 0;
        __syncthreads();
        const int e0 = c * CHUNK;
        const int n  = min(CHUNK, E - e0);
        for (int i = tid; i < n; i += 256) {
            int o = ((const int2*)idx)[e0 + i].x;
            atomicAdd(&hist[o >> 8], 1);  // LDS atomic
        }
        __syncthreads();
        for (int i = tid; i < NBIN_S; i += 256)
            counts[i * NCHUNK + c] = hist[i];  // bin-major for the scan
    }
}

// ---------------------------------------------------------------------------
// Scan pass A over counts[LEN_CNT]: per-256-chunk exclusive scan in place.
// ---------------------------------------------------------------------------
__global__ __launch_bounds__(256) void scanA_kernel(int* __restrict__ a,
                                                    int* __restrict__ bsum) {
    __shared__ int sh[256];
    const int tid = threadIdx.x;
    int g = blockIdx.x * 256 + tid;
    int v = (g < LEN_CNT) ? a[g] : 0;
    sh[tid] = v;
    __syncthreads();
#pragma unroll
    for (int off = 1; off < 256; off <<= 1) {
        int x = 0;
        if (tid >= off) x = sh[tid - off];
        __syncthreads();
        if (tid >= off) sh[tid] += x;
        __syncthreads();
    }
    int incl = sh[tid];
    if (g < LEN_CNT) a[g] = incl - v;
    if (tid == 255) bsum[blockIdx.x] = incl;
}

// ---------------------------------------------------------------------------
// Scan pass BC: each block adds sum(bsum[0..bi)).  SCA(151) < 256.
// ---------------------------------------------------------------------------
__global__ __launch_bounds__(256) void scanBC_kernel(int* __restrict__ a,
                                                     const int* __restrict__ bsum) {
    __shared__ int sh[256];
    const int bi  = blockIdx.x;
    const int tid = threadIdx.x;
    sh[tid] = (tid < bi) ? bsum[tid] : 0;
    __syncthreads();
#pragma unroll
    for (int off = 128; off >= 1; off >>= 1) {
        if (tid < off) sh[tid] += sh[tid + off];
        __syncthreads();
    }
    const int offset = sh[0];
    int g = bi * 256 + tid;
    if (g < LEN_CNT) a[g] += offset;
}

// ---------------------------------------------------------------------------
// binscatter: chunk c places its edges into per-(bin,chunk) runs.
// Entry: {x: loc(8b)<<20 | e(20b), y: in_node}.
// ---------------------------------------------------------------------------
__global__ __launch_bounds__(512) void binscatter_kernel(const int* __restrict__ idx,
                                                         const int* __restrict__ offs,
                                                         uint2* __restrict__ ent) {
    __shared__ int cur[NBIN_S];
    const int tid = threadIdx.x;
    const int c   = blockIdx.x;
    for (int i = tid; i < NBIN_S; i += 512) cur[i] = offs[i * NCHUNK + c];
    __syncthreads();
    const int e0 = c * CHUNK;
    const int n  = min(CHUNK, E - e0);
    for (int i = tid; i < n; i += 512) {
        int2 oi = ((const int2*)idx)[e0 + i];  // {out, in}, coalesced 8B
        int bin = oi.x >> 8;
        int loc = oi.x & 255;
        int pos = atomicAdd(&cur[bin], 1);
        ent[pos] = make_uint2(((unsigned)loc << 20) | (unsigned)(e0 + i),
                              (unsigned)oi.y);
    }
}

// ---------------------------------------------------------------------------
// permfix: block = one bin (256 nodes). (1) LDS 256-hist + scan -> node
// starts (writes global start[]); (2) scatter entries to exact node-sorted
// slots as ONE packed uint2 {in, e} (single 8B write instead of two 4B
// scatters). Writes confined to the bin's block-exclusive ~33KB window.
// ---------------------------------------------------------------------------
__global__ __launch_bounds__(512) void permfix_kernel(const int* __restrict__ offs,
                                                      const uint2* __restrict__ ent,
                                                      int* __restrict__ start_g,
                                                      uint2* __restrict__ ent2) {
    __shared__ int hist[256];
    __shared__ int sc[256];
    __shared__ int cur[256];
    const int tid = threadIdx.x;
    const int b   = blockIdx.x;
    const int W0  = offs[b * NCHUNK];
    const int W1  = (b + 1 < NBIN_S) ? offs[(b + 1) * NCHUNK] : E;

    if (tid < 256) hist[tid] = 0;
    __syncthreads();
    for (int i = W0 + tid; i < W1; i += 512)
        atomicAdd(&hist[ent[i].x >> 20], 1);
    __syncthreads();

    // inclusive scan of hist[256] on threads 0-255 (512-thread-safe barriers)
    if (tid < 256) sc[tid] = hist[tid];
    __syncthreads();
    for (int off = 1; off < 256; off <<= 1) {
        int x = 0;
        if (tid < 256 && tid >= off) x = sc[tid - off];
        __syncthreads();
        if (tid < 256 && tid >= off) sc[tid] += x;
        __syncthreads();
    }
    if (tid < 256) {
        int s = W0 + sc[tid] - hist[tid];  // exclusive
        int g = b * 256 + tid;
        if (g < N_OUT) start_g[g] = s;
        cur[tid] = s;
    }
    if (b == NBIN_S - 1 && tid == 0) start_g[N_OUT] = E;
    __syncthreads();

    for (int i = W0 + tid; i < W1; i += 512) {
        uint2 u = ent[i];
        int loc = (int)(u.x >> 20);
        int e   = (int)(u.x & 0xFFFFFu);
        int pos = atomicAdd(&cur[loc], 1);
        ent2[pos] = make_uint2(u.y, (unsigned)e);  // {in, e} packed
    }
}

// ---------------------------------------------------------------------------
// Aggregate: block = 4 waves = 16 output nodes.
//  Phase 1 (per wave, 4 nodes, lane=c):
//    preload 64 packed {in,e} entries via NONTEMPORAL 8B loads (stream must
//    not evict the nf/ef gather tables from L2), readlane-broadcast;
//    4-edge unroll -> 4 independent 128 B nf gathers in flight; weights via
//    wave-uniform scalar 16B loads from efh[e*8] (fp16: 4 edges/64B line,
//    halves the random weight-line miss traffic vs fp32 ef_T).
//  Phase 2 (per wave, one 16-col f-tile):
//    out_tile(16x64) = A(16x512) @ K_T^T via 16 chained mfma_f32_16x16x32_bf16
//    with nontemporal out stores.
// ---------------------------------------------------------------------------
__global__ __launch_bounds__(256) void aggregate_kernel(const unsigned short* __restrict__ nf_bf,
                                                        const unsigned short* __restrict__ K_T,
                                                        const int* __restrict__ start,
                                                        const uint2* __restrict__ ent2,
                                                        const _Float16* __restrict__ efh,
                                                        const float* __restrict__ bias,
                                                        float* __restrict__ out) {
    __shared__ unsigned short A_lds[16][520];  // +8 pad

    const int wave = threadIdx.x >> 6;
    const int lane = threadIdx.x & 63;
    const int node_base = blockIdx.x * 16;  // 50000 = 3125*16 exact

    const unsigned long long* ent2q = (const unsigned long long*)ent2;
    const f16x8* efh8 = (const f16x8*)efh;

    // ---- Phase 1: segment aggregation ----
    for (int q = 0; q < 4; ++q) {
        const int m = wave * 4 + q;
        const int o = node_base + m;
        const int s0 = __builtin_amdgcn_readfirstlane(start[o]);
        const int s1 = __builtin_amdgcn_readfirstlane(start[o + 1]);

        float acc[8] = {0.f, 0.f, 0.f, 0.f, 0.f, 0.f, 0.f, 0.f};

        for (int base = s0; base < s1; base += 64) {
            const int cnt = min(64, s1 - base);
            // coalesced nontemporal preload of this chunk's {in, e} pairs
            unsigned long long v = 0;
            if (base + lane < s1)
                v = __builtin_nontemporal_load(ent2q + base + lane);
            int iv = (int)(unsigned)(v & 0xFFFFFFFFull);
            int ev = (int)(unsigned)(v >> 32);

            int j = 0;
            for (; j + 4 <= cnt; j += 4) {
                const int i0 = __builtin_amdgcn_readlane(iv, j + 0);
                const int i1 = __builtin_amdgcn_readlane(iv, j + 1);
                const int i2 = __builtin_amdgcn_readlane(iv, j + 2);
                const int i3 = __builtin_amdgcn_readlane(iv, j + 3);
                // 4 independent 128 B gathers in flight
                float x0 = bf2f(nf_bf[(size_t)i0 * 64 + lane]);
                float x1 = bf2f(nf_bf[(size_t)i1 * 64 + lane]);
                float x2 = bf2f(nf_bf[(size_t)i2 * 64 + lane]);
                float x3 = bf2f(nf_bf[(size_t)i3 * 64 + lane]);
                // wave-uniform scalar weight loads (16B fp16 each)
                f16x8 w0 = efh8[(size_t)__builtin_amdgcn_readlane(ev, j + 0)];
                f16x8 w1 = efh8[(size_t)__builtin_amdgcn_readlane(ev, j + 1)];
                f16x8 w2 = efh8[(size_t)__builtin_amdgcn_readlane(ev, j + 2)];
                f16x8 w3 = efh8[(size_t)__builtin_amdgcn_readlane(ev, j + 3)];
#pragma unroll
                for (int t = 0; t < T; ++t) {
                    acc[t] += (float)w0[t] * x0;
                    acc[t] += (float)w1[t] * x1;
                    acc[t] += (float)w2[t] * x2;
                    acc[t] += (float)w3[t] * x3;
                }
            }
            for (; j < cnt; ++j) {
                const int i0 = __builtin_amdgcn_readlane(iv, j);
                float x0 = bf2f(nf_bf[(size_t)i0 * 64 + lane]);
                f16x8 w0 = efh8[(size_t)__builtin_amdgcn_readlane(ev, j)];
#pragma unroll
                for (int t = 0; t < T; ++t) acc[t] += (float)w0[t] * x0;
            }
        }

#pragma unroll
        for (int t = 0; t < T; ++t) A_lds[m][t * 64 + lane] = f2bf(acc[t]);
    }
    __syncthreads();

    // ---- Phase 2: MFMA epilogue; wave handles f-tile [wave*16, wave*16+16) ----
    const int mrow = lane & 15;
    const int kb   = lane >> 4;
    const int fcol = wave * 16 + mrow;

    f32x4 acc4 = {0.f, 0.f, 0.f, 0.f};
#pragma unroll
    for (int s = 0; s < 16; ++s) {
        const int k0 = s * 32 + kb * 8;
        short8 a = *(const short8*)&A_lds[mrow][k0];
        short8 b = *(const short8*)(K_T + (size_t)fcol * 512 + k0);
        acc4 = __builtin_amdgcn_mfma_f32_16x16x32_bf16(a, b, acc4, 0, 0, 0);
    }

    const float bv = bias[fcol];
#pragma unroll
    for (int r = 0; r < 4; ++r) {
        const int m = kb * 4 + r;
        __builtin_nontemporal_store(acc4[r] + bv,
                                    &out[(size_t)(node_base + m) * F + fcol]);
    }
}

// ---------------------------------------------------------------------------
extern "C" void kernel_launch(void* const* d_in, const int* in_sizes, int n_in,
                              void* d_out, int out_size, void* d_ws, size_t ws_size,
                              hipStream_t stream) {
    const float* nf   = (const float*)d_in[0];  // (N_IN, C)
    const float* ef   = (const float*)d_in[1];  // (T, E)
    const int*   idx  = (const int*)d_in[2];    // (E, 2) int32 on device
    const float* Kmat = (const float*)d_in[3];  // (T, C, F)
    const float* bias = (const float*)d_in[4];  // (F,)
    float*       out  = (float*)d_out;          // (N_OUT, F)

    char* ws = (char*)d_ws;
    unsigned short* nf_bf  = (unsigned short*)(ws + OFF_NFBF);
    unsigned short* K_T    = (unsigned short*)(ws + OFF_KT);
    int*            counts = (int*)(ws + OFF_CNT);    // becomes offs[]
    int*            bsum   = (int*)(ws + OFF_BSUM);
    int*            start  = (int*)(ws + OFF_START);
    _Float16*       efh    = (_Float16*)(ws + OFF_EFH);
    uint2*          ent    = (uint2*)(ws + OFF_ENT);
    uint2*          ent2   = (uint2*)(ws + OFF_ENT2);

    // no memset needed: counts/start/ent are fully written by the pipeline
    prep_kernel<<<NF_BLOCKS + KT_BLOCKS + ET_BLOCKS + BH_BLOCKS, 256, 0, stream>>>(
        nf, Kmat, ef, idx, nf_bf, K_T, efh, counts);
    scanA_kernel<<<SCA, 256, 0, stream>>>(counts, bsum);
    scanBC_kernel<<<SCA, 256, 0, stream>>>(counts, bsum);
    binscatter_kernel<<<NCHUNK, 512, 0, stream>>>(idx, counts, ent);
    permfix_kernel<<<NBIN_S, 512, 0, stream>>>(counts, ent, start, ent2);
    aggregate_kernel<<<N_OUT / 16, 256, 0, stream>>>(
        nf_bf, K_T, start, ent2, efh, bias, out);
}